// Round 18
// baseline (547.021 us; speedup 1.0000x reference)
//
#include <hip/hip_runtime.h>
#include <hip/hip_bf16.h>

// GraphLSTM v14 = round-17 + fragment-major weight layout (conflict-free).
// Round-17 counters: C 308us, VALU 66% + MFMA 25% (~90% issue), but 43.5M
// LDS bank conflicts -- the weight b128 reads are 8-way conflicted (row
// stride 84 dwords -> banks 4*((5c+g4)%8)). Fix: pack Wg/Wc so each MFMA
// B-fragment slice is 64 contiguous 16B chunks indexed by lane:
//   W[(q*4+g)*KS + ks][lane][8]  -> LDS read = base + lane*16B (2-way, free)
// Staging becomes a straight coalesced copy; lWc 86->80KB, lWg 53->48KB.
// Applied to A, C-pt, and rc fallback (shared buffers). All else frozen.

#define Sx    32
#define Nx    65536
#define OUTx  5
#define KG    96
#define KC    160
#define GRIDA 256             // A/C blocks (16 waves)
#define TPB   1024
#define NWAVE (GRIDA * 16)    // 4096 per-wave partial slots
#define GRIDF 512             // rc fallback geometry
#define TPBF  512

typedef __attribute__((ext_vector_type(4))) float f32x4;
typedef __attribute__((ext_vector_type(8))) short bf16x8;
typedef unsigned short ushort;
typedef unsigned int uint;

__device__ __forceinline__ float sigm(float x) {
    return __builtin_amdgcn_rcpf(1.f + __expf(-x));
}
__device__ __forceinline__ float tanh_fast(float x) {
    return fmaf(-2.f, __builtin_amdgcn_rcpf(1.f + __expf(2.f * x)), 1.f);
}
__device__ __forceinline__ ushort f2b(float x) {
    uint u = __float_as_uint(x);
    u += 0x7fffu + ((u >> 16) & 1u);   // RNE
    return (ushort)(u >> 16);
}
__device__ __forceinline__ ushort f2b_n(float x) {   // native RNE cast
    __hip_bfloat16 b = __float2bfloat16(x);
    return *reinterpret_cast<ushort*>(&b);
}
__device__ __forceinline__ int swz(int row, int col) {
    return col ^ (((row >> 2) & 3) << 4);
}

// ---------------- weight prep (fragment-major packing) ----------------
__global__ __launch_bounds__(256) void k_prep(
    const float* __restrict__ Wih_g, const float* __restrict__ Whh_g,
    const float* __restrict__ bih_g, const float* __restrict__ bhh_g,
    const float* __restrict__ wgr,
    const float* __restrict__ Wih_c, const float* __restrict__ Whh_c,
    const float* __restrict__ bih_c, const float* __restrict__ bhh_c,
    const float* __restrict__ Wout,
    ushort* __restrict__ Wg, ushort* __restrict__ Wc,
    ushort* __restrict__ WoB,
    float* __restrict__ Wfold2,
    float* __restrict__ bsum_g, float* __restrict__ bC0)
{
    const int tid = blockIdx.x * 256 + threadIdx.x;
    const int nt = gridDim.x * 256;
    // Wg packed: [(q*4+g)*3 + ks][lane(=g4*16+c)][j:8]
    for (int o = tid; o < 256 * KG; o += nt) {
        const int j = o & 7, lane = (o >> 3) & 63;
        const int ks = (o >> 9) % 3, gq = (o >> 9) / 3;
        const int q = gq >> 2, g = gq & 3;
        const int col = 16 * (4 * g + q) + (lane & 15);
        const int k = ks * 32 + (lane >> 4) * 8 + j;
        float v = (k < 32) ? Wih_g[col * 32 + k] : Whh_g[col * 64 + (k - 32)];
        Wg[o] = f2b(v);
    }
    // Wc packed: [(q*4+g)*5 + ks][lane][j:8]
    for (int o = tid; o < 256 * KC; o += nt) {
        const int j = o & 7, lane = (o >> 3) & 63;
        const int ks = (o >> 9) % 5, gq = (o >> 9) / 5;
        const int q = gq >> 2, g = gq & 3;
        const int col = 16 * (4 * g + q) + (lane & 15);
        const int k = ks * 32 + (lane >> 4) * 8 + j;
        float v;
        if (k < 32) v = Wih_c[col * 64 + k];
        else if (k < 96) {
            int d = k - 32; float a = 0.f;
            for (int jj = 0; jj < 32; ++jj)
                a = fmaf(wgr[d * 32 + jj], Wih_c[col * 64 + 32 + jj], a);
            v = -a;
        } else v = Whh_c[col * 64 + (k - 96)];
        Wc[o] = f2b(v);
    }
    for (int idx = tid; idx < 16 * 64; idx += nt) {
        int col = idx >> 6, k = idx & 63;
        WoB[idx] = (col < OUTx) ? f2b(Wout[col * 64 + k]) : (ushort)0;
    }
    for (int idx = tid; idx < 64 * 256; idx += nt) {
        int k = idx >> 8, col = idx & 255;
        float a = 0.f;
        for (int j = 0; j < 32; ++j)
            a = fmaf(wgr[k * 32 + j], Wih_c[col * 64 + 32 + j], a);
        Wfold2[idx] = a;
    }
    if (tid < 256) {
        bsum_g[tid] = bih_g[tid] + bhh_g[tid];
        bC0[tid]    = bih_c[tid] + bhh_c[tid];
    }
}

// ---------------- A: graph LSTM, all steps -------------------------------
template <int PW>
__global__ __launch_bounds__(TPB, 2) void k_graph_all(
    const float* __restrict__ input,
    const float* __restrict__ gh0, const float* __restrict__ gc0,
    const float* __restrict__ Wge, const float* __restrict__ bge,
    const ushort* __restrict__ Wg, const float* __restrict__ bsum_g,
    float* __restrict__ partials,     // PW: [S][NWAVE][64] else [S][GRIDA][64]
    ushort* __restrict__ ghb,
    float* __restrict__ ghf, float* __restrict__ gcf)
{
    const int tid = threadIdx.x;
    const int wave = tid >> 6, lane = tid & 63;
    const int c = lane & 15, g4 = lane >> 4;
    const int nb = blockIdx.x * 256 + wave * 16;
    const int na = nb + c;

    __shared__ __align__(16) ushort lWg[256 * KG];       // 48 KB packed
    __shared__ __align__(16) ushort t_lds[16][16][72];
    __shared__ float wsum[PW ? 1 : 2][16][64];

    {   // straight coalesced copy (packed layout)
        const uint* src = (const uint*)Wg;
        uint* dst = (uint*)lWg;
        for (int i = tid; i < 256 * (KG / 2); i += TPB) dst[i] = src[i];
    }
    __syncthreads();

    float bsg[4][4];
#pragma unroll
    for (int q = 0; q < 4; ++q)
#pragma unroll
        for (int g = 0; g < 4; ++g)
            bsg[q][g] = bsum_g[64 * g + 16 * q + c];

    float gcr[4][4];
#pragma unroll
    for (int q = 0; q < 4; ++q)
#pragma unroll
        for (int r = 0; r < 4; ++r)
            gcr[q][r] = gc0[(nb + 4 * g4 + r) * 64 + 16 * q + c];
    bf16x8 agh0, agh1;
#pragma unroll
    for (int j = 0; j < 8; ++j) {
        agh0[j] = (short)f2b(gh0[na * 64 + g4 * 8 + j]);
        agh1[j] = (short)f2b(gh0[na * 64 + 32 + g4 * 8 + j]);
    }
    const int lane8 = lane * 8;

#pragma unroll 1
    for (int t = 0; t < Sx; ++t) {
        const float* frame = input + (size_t)t * Nx * 2;
        const float f0 = frame[2 * na], f1 = frame[2 * na + 1];
        const int lastt = (t == Sx - 1);
        bf16x8 a0;
#pragma unroll
        for (int j = 0; j < 8; ++j) {
            const int k = g4 * 8 + j;
            float v = fmaf(f1, Wge[2 * k + 1], fmaf(f0, Wge[2 * k], bge[k]));
            a0[j] = (short)f2b_n(fmaxf(v, 0.f));
        }
        float hsq[4];
#pragma unroll 2
        for (int q = 0; q < 4; ++q) {
            f32x4 acc[4];
#pragma unroll
            for (int g = 0; g < 4; ++g) {
                acc[g] = (f32x4){0.f, 0.f, 0.f, 0.f};
                const ushort* wp = lWg + ((q * 4 + g) * 3) * 512 + lane8;
                bf16x8 b0 = *(const bf16x8*)(wp);
                bf16x8 b1 = *(const bf16x8*)(wp + 512);
                bf16x8 b2 = *(const bf16x8*)(wp + 1024);
                acc[g] = __builtin_amdgcn_mfma_f32_16x16x32_bf16(a0,   b0, acc[g], 0, 0, 0);
                acc[g] = __builtin_amdgcn_mfma_f32_16x16x32_bf16(agh0, b1, acc[g], 0, 0, 0);
                acc[g] = __builtin_amdgcn_mfma_f32_16x16x32_bf16(agh1, b2, acc[g], 0, 0, 0);
            }
            const int d = 16 * q + c;
            float s_r = 0.f;
#pragma unroll
            for (int r = 0; r < 4; ++r) {
                const float ai = acc[0][r] + bsg[q][0], af = acc[1][r] + bsg[q][1],
                            ag = acc[2][r] + bsg[q][2], ao = acc[3][r] + bsg[q][3];
                const float c2 = fmaf(sigm(af), gcr[q][r], sigm(ai) * tanh_fast(ag));
                gcr[q][r] = c2;
                const float h2 = sigm(ao) * tanh_fast(c2);
                const int row = 4 * g4 + r;
                t_lds[wave][row][swz(row, 16 * q + c)] = f2b_n(h2);
                if (lastt) {
                    const int n = nb + row;
                    ghf[n * 64 + d] = h2;
                    gcf[n * 64 + d] = c2;
                }
                s_r += h2;
            }
            hsq[q] = s_r;
        }
#pragma unroll
        for (int q = 0; q < 4; ++q) {
            float v = hsq[q];
            v += __shfl_xor(v, 16);
            v += __shfl_xor(v, 32);
            hsq[q] = v;
        }
        if (PW) {
            float v = (g4 == 0) ? hsq[0] : (g4 == 1) ? hsq[1]
                    : (g4 == 2) ? hsq[2] : hsq[3];
            const int gw = blockIdx.x * 16 + wave;
            partials[((size_t)t * NWAVE + gw) * 64 + 16 * g4 + c] = v;
        } else {
            if (g4 == 0) {
#pragma unroll
                for (int q = 0; q < 4; ++q) wsum[t & 1][wave][16 * q + c] = hsq[q];
            }
            __syncthreads();
        }
        agh0 = *(const bf16x8*)(&t_lds[wave][c][swz(c, g4 * 8)]);
        agh1 = *(const bf16x8*)(&t_lds[wave][c][swz(c, 32 + g4 * 8)]);
        if (ghb) {
            ushort* gp = ghb + ((size_t)t * Nx + na) * 64 + g4 * 8;
            *(bf16x8*)(gp)      = agh0;
            *(bf16x8*)(gp + 32) = agh1;
        }
        if (!PW) {
            if (tid < 64) {
                float a = 0.f;
#pragma unroll
                for (int w8 = 0; w8 < 16; ++w8) a += wsum[t & 1][w8][tid];
                partials[((size_t)t * GRIDA + blockIdx.x) * 64 + tid] = a;
            }
        }
    }
}

// ---------------- B1: first-stage reduce (512 blocks) ----------------------
__global__ __launch_bounds__(256) void k_red1(
    const float* __restrict__ partials,   // [S][NWAVE][64]
    float* __restrict__ p2)               // [S][16][64]
{
    const int t = blockIdx.x >> 4, s = blockIdx.x & 15;
    const int tid = threadIdx.x;
    const int d = tid & 63, j = tid >> 6;
    __shared__ float red[4][64];
    const float* bp = partials + ((size_t)t * NWAVE + s * 256) * 64;
    float a = 0.f;
    for (int b = j; b < 256; b += 4)
        a += bp[b * 64 + d];
    red[j][d] = a;
    __syncthreads();
    if (tid < 64)
        p2[((size_t)t * 16 + s) * 64 + tid] =
            red[0][tid] + red[1][tid] + red[2][tid] + red[3][tid];
}

// ---------------- B2: per-step bias ----------------------------------------
__global__ __launch_bounds__(256) void k_bias(
    const float* __restrict__ partials,   // [S][nw][64]
    int nw,
    const float* __restrict__ Wfold2, const float* __restrict__ bC0,
    float* __restrict__ bias_all)         // [S][256]
{
    const int t = blockIdx.x, tid = threadIdx.x;
    __shared__ float red[4][64];
    __shared__ float S[64];
    const int d = tid & 63, j = tid >> 6;
    float a = 0.f;
    for (int b = j; b < nw; b += 4)
        a += partials[((size_t)t * nw + b) * 64 + d];
    red[j][d] = a;
    __syncthreads();
    if (tid < 64) S[tid] = red[0][tid] + red[1][tid] + red[2][tid] + red[3][tid];
    __syncthreads();
    float bv = bC0[tid];
#pragma unroll
    for (int k = 0; k < 64; ++k) bv = fmaf(S[k], Wfold2[k * 256 + tid], bv);
    bias_all[t * 256 + tid] = bv;
}

// ---------------- C (pass-through): cell LSTM only ------------------------
__global__ __launch_bounds__(TPB, 2) void k_cell_pt(
    const float* __restrict__ input,
    const ushort* __restrict__ ghb,
    const float* __restrict__ ch0, const float* __restrict__ cc0,
    const float* __restrict__ Wdy, const float* __restrict__ bdy,
    const ushort* __restrict__ Wc, const float* __restrict__ bias_all,
    const ushort* __restrict__ WoB, const float* __restrict__ bo5,
    float* __restrict__ out0,
    float* __restrict__ chf, float* __restrict__ ccf)
{
    const int tid = threadIdx.x;
    const int wave = tid >> 6, lane = tid & 63;
    const int c = lane & 15, g4 = lane >> 4;
    const int nb = blockIdx.x * 256 + wave * 16;
    const int na = nb + c;

    __shared__ __align__(16) ushort lWc[256 * KC];       // 80 KB packed
    __shared__ __align__(16) ushort t_lds[16][16][72];

    {
        const uint* src2 = (const uint*)Wc;
        uint* dst2 = (uint*)lWc;
        for (int i = tid; i < 256 * (KC / 2); i += TPB) dst2[i] = src2[i];
    }
    __syncthreads();

    float ccr[4][4];
#pragma unroll
    for (int q = 0; q < 4; ++q)
#pragma unroll
        for (int r = 0; r < 4; ++r)
            ccr[q][r] = cc0[(nb + 4 * g4 + r) * 64 + 16 * q + c];
    bf16x8 ach0, ach1;
#pragma unroll
    for (int j = 0; j < 8; ++j) {
        ach0[j] = (short)f2b(ch0[na * 64 + g4 * 8 + j]);
        ach1[j] = (short)f2b(ch0[na * 64 + 32 + g4 * 8 + j]);
    }
    bf16x8 woB0 = *(const bf16x8*)(WoB + c * 64 + g4 * 8);
    bf16x8 woB1 = *(const bf16x8*)(WoB + c * 64 + 32 + g4 * 8);
    const float bo_c = (c < OUTx) ? bo5[c] : 0.f;
    const int lane8 = lane * 8;

#pragma unroll 1
    for (int t = 0; t < Sx; ++t) {
        const float* frame = input + (size_t)t * Nx * 2;
        const float f0 = frame[2 * na], f1 = frame[2 * na + 1];
        const int lastt = (t == Sx - 1);

        const ushort* gp = ghb + ((size_t)t * Nx + na) * 64 + g4 * 8;
        bf16x8 agh0 = *(const bf16x8*)(gp);
        bf16x8 agh1 = *(const bf16x8*)(gp + 32);

        bf16x8 a0c;
#pragma unroll
        for (int j = 0; j < 8; ++j) {
            const int k = g4 * 8 + j;
            float v = fmaf(f1, Wdy[2 * k + 1], fmaf(f0, Wdy[2 * k], bdy[k]));
            a0c[j] = (short)f2b_n(fmaxf(v, 0.f));
        }
#pragma unroll 1
        for (int q = 0; q < 4; ++q) {
            f32x4 acc[4];
#pragma unroll
            for (int g = 0; g < 4; ++g) {
                acc[g] = (f32x4){0.f, 0.f, 0.f, 0.f};
                const ushort* wp = lWc + ((q * 4 + g) * 5) * 512 + lane8;
                bf16x8 b0 = *(const bf16x8*)(wp);
                bf16x8 b1 = *(const bf16x8*)(wp + 512);
                bf16x8 b2 = *(const bf16x8*)(wp + 1024);
                bf16x8 b3 = *(const bf16x8*)(wp + 1536);
                bf16x8 b4 = *(const bf16x8*)(wp + 2048);
                acc[g] = __builtin_amdgcn_mfma_f32_16x16x32_bf16(a0c,  b0, acc[g], 0, 0, 0);
                acc[g] = __builtin_amdgcn_mfma_f32_16x16x32_bf16(agh0, b1, acc[g], 0, 0, 0);
                acc[g] = __builtin_amdgcn_mfma_f32_16x16x32_bf16(agh1, b2, acc[g], 0, 0, 0);
                acc[g] = __builtin_amdgcn_mfma_f32_16x16x32_bf16(ach0, b3, acc[g], 0, 0, 0);
                acc[g] = __builtin_amdgcn_mfma_f32_16x16x32_bf16(ach1, b4, acc[g], 0, 0, 0);
            }
            const int d = 16 * q + c;
            const float bi = bias_all[t * 256 + d],
                        bf = bias_all[t * 256 + 64 + d],
                        bg = bias_all[t * 256 + 128 + d],
                        bov = bias_all[t * 256 + 192 + d];
#pragma unroll
            for (int r = 0; r < 4; ++r) {
                const float ai = acc[0][r] + bi, af = acc[1][r] + bf,
                            ag = acc[2][r] + bg, ao = acc[3][r] + bov;
                const float c2 = fmaf(sigm(af), ccr[q][r], sigm(ai) * tanh_fast(ag));
                ccr[q][r] = c2;
                const float h2 = sigm(ao) * tanh_fast(c2);
                const int row = 4 * g4 + r;
                t_lds[wave][row][swz(row, 16 * q + c)] = f2b_n(h2);
                if (lastt) {
                    const int n = nb + row;
                    chf[n * 64 + d] = h2;
                    ccf[n * 64 + d] = c2;
                }
            }
        }
        ach0 = *(const bf16x8*)(&t_lds[wave][c][swz(c, g4 * 8)]);
        ach1 = *(const bf16x8*)(&t_lds[wave][c][swz(c, 32 + g4 * 8)]);

        {
            f32x4 oa = (f32x4){0.f, 0.f, 0.f, 0.f};
            oa = __builtin_amdgcn_mfma_f32_16x16x32_bf16(ach0, woB0, oa, 0, 0, 0);
            oa = __builtin_amdgcn_mfma_f32_16x16x32_bf16(ach1, woB1, oa, 0, 0, 0);
            if (c < OUTx) {
                float* outp = out0 + (size_t)t * Nx * OUTx;
#pragma unroll
                for (int r = 0; r < 4; ++r)
                    outp[(nb + 4 * g4 + r) * OUTx + c] = oa[r] + bo_c;
            }
        }
    }
}

// ---------------- C (fallback): graph recompute + cell --------------------
__global__ __launch_bounds__(TPBF, 2) void k_cell_rc(
    const float* __restrict__ input,
    const float* __restrict__ gh0, const float* __restrict__ gc0,
    const float* __restrict__ ch0, const float* __restrict__ cc0,
    const float* __restrict__ Wge, const float* __restrict__ bge,
    const ushort* __restrict__ Wg, const float* __restrict__ bsum_g,
    const float* __restrict__ Wdy, const float* __restrict__ bdy,
    const ushort* __restrict__ Wc, const float* __restrict__ bias_all,
    const ushort* __restrict__ WoB, const float* __restrict__ bo5,
    float* __restrict__ out0,
    float* __restrict__ chf, float* __restrict__ ccf)
{
    const int tid = threadIdx.x;
    const int wave = tid >> 6, lane = tid & 63;
    const int c = lane & 15, g4 = lane >> 4;
    const int nb = blockIdx.x * 128 + wave * 16;
    const int na = nb + c;

    __shared__ __align__(16) ushort lWg[256 * KG];
    __shared__ __align__(16) ushort lWc[256 * KC];
    __shared__ __align__(16) ushort t_lds[8][16][72];

    {
        const uint* src = (const uint*)Wg;
        uint* dst = (uint*)lWg;
        for (int i = tid; i < 256 * (KG / 2); i += TPBF) dst[i] = src[i];
        const uint* src2 = (const uint*)Wc;
        uint* dst2 = (uint*)lWc;
        for (int i = tid; i < 256 * (KC / 2); i += TPBF) dst2[i] = src2[i];
    }
    __syncthreads();

    float gcr[4][4], ccr[4][4];
#pragma unroll
    for (int q = 0; q < 4; ++q)
#pragma unroll
        for (int r = 0; r < 4; ++r) {
            const int n = nb + 4 * g4 + r, d = 16 * q + c;
            gcr[q][r] = gc0[n * 64 + d];
            ccr[q][r] = cc0[n * 64 + d];
        }
    bf16x8 agh0, agh1, ach0, ach1;
#pragma unroll
    for (int j = 0; j < 8; ++j) {
        agh0[j] = (short)f2b(gh0[na * 64 + g4 * 8 + j]);
        agh1[j] = (short)f2b(gh0[na * 64 + 32 + g4 * 8 + j]);
        ach0[j] = (short)f2b(ch0[na * 64 + g4 * 8 + j]);
        ach1[j] = (short)f2b(ch0[na * 64 + 32 + g4 * 8 + j]);
    }
    bf16x8 woB0 = *(const bf16x8*)(WoB + c * 64 + g4 * 8);
    bf16x8 woB1 = *(const bf16x8*)(WoB + c * 64 + 32 + g4 * 8);
    const float bo_c = (c < OUTx) ? bo5[c] : 0.f;
    const int lane8 = lane * 8;

#pragma unroll 1
    for (int t = 0; t < Sx; ++t) {
        const float* frame = input + (size_t)t * Nx * 2;
        const float f0 = frame[2 * na], f1 = frame[2 * na + 1];
        const int lastt = (t == Sx - 1);

        bf16x8 a0;
#pragma unroll
        for (int j = 0; j < 8; ++j) {
            const int k = g4 * 8 + j;
            float v = fmaf(f1, Wge[2 * k + 1], fmaf(f0, Wge[2 * k], bge[k]));
            a0[j] = (short)f2b(fmaxf(v, 0.f));
        }
#pragma unroll 1
        for (int q = 0; q < 4; ++q) {
            f32x4 acc[4];
#pragma unroll
            for (int g = 0; g < 4; ++g) {
                acc[g] = (f32x4){0.f, 0.f, 0.f, 0.f};
                const ushort* wp = lWg + ((q * 4 + g) * 3) * 512 + lane8;
                bf16x8 b0 = *(const bf16x8*)(wp);
                bf16x8 b1 = *(const bf16x8*)(wp + 512);
                bf16x8 b2 = *(const bf16x8*)(wp + 1024);
                acc[g] = __builtin_amdgcn_mfma_f32_16x16x32_bf16(a0,   b0, acc[g], 0, 0, 0);
                acc[g] = __builtin_amdgcn_mfma_f32_16x16x32_bf16(agh0, b1, acc[g], 0, 0, 0);
                acc[g] = __builtin_amdgcn_mfma_f32_16x16x32_bf16(agh1, b2, acc[g], 0, 0, 0);
            }
            const int d = 16 * q + c;
            const float bi = bsum_g[d], bf = bsum_g[64 + d],
                        bg = bsum_g[128 + d], bo = bsum_g[192 + d];
#pragma unroll
            for (int r = 0; r < 4; ++r) {
                const float ai = acc[0][r] + bi, af = acc[1][r] + bf,
                            ag = acc[2][r] + bg, ao = acc[3][r] + bo;
                const float c2 = fmaf(sigm(af), gcr[q][r], sigm(ai) * tanh_fast(ag));
                gcr[q][r] = c2;
                const float h2 = sigm(ao) * tanh_fast(c2);
                t_lds[wave][4 * g4 + r][16 * q + c] = f2b(h2);
            }
        }
        agh0 = *(const bf16x8*)(&t_lds[wave][c][g4 * 8]);
        agh1 = *(const bf16x8*)(&t_lds[wave][c][32 + g4 * 8]);

        bf16x8 a0c;
#pragma unroll
        for (int j = 0; j < 8; ++j) {
            const int k = g4 * 8 + j;
            float v = fmaf(f1, Wdy[2 * k + 1], fmaf(f0, Wdy[2 * k], bdy[k]));
            a0c[j] = (short)f2b(fmaxf(v, 0.f));
        }
#pragma unroll 1
        for (int q = 0; q < 4; ++q) {
            f32x4 acc[4];
#pragma unroll
            for (int g = 0; g < 4; ++g) {
                acc[g] = (f32x4){0.f, 0.f, 0.f, 0.f};
                const ushort* wp = lWc + ((q * 4 + g) * 5) * 512 + lane8;
                bf16x8 b0 = *(const bf16x8*)(wp);
                bf16x8 b1 = *(const bf16x8*)(wp + 512);
                bf16x8 b2 = *(const bf16x8*)(wp + 1024);
                bf16x8 b3 = *(const bf16x8*)(wp + 1536);
                bf16x8 b4 = *(const bf16x8*)(wp + 2048);
                acc[g] = __builtin_amdgcn_mfma_f32_16x16x32_bf16(a0c,  b0, acc[g], 0, 0, 0);
                acc[g] = __builtin_amdgcn_mfma_f32_16x16x32_bf16(agh0, b1, acc[g], 0, 0, 0);
                acc[g] = __builtin_amdgcn_mfma_f32_16x16x32_bf16(agh1, b2, acc[g], 0, 0, 0);
                acc[g] = __builtin_amdgcn_mfma_f32_16x16x32_bf16(ach0, b3, acc[g], 0, 0, 0);
                acc[g] = __builtin_amdgcn_mfma_f32_16x16x32_bf16(ach1, b4, acc[g], 0, 0, 0);
            }
            const int d = 16 * q + c;
            const float bi = bias_all[t * 256 + d],
                        bf = bias_all[t * 256 + 64 + d],
                        bg = bias_all[t * 256 + 128 + d],
                        bov = bias_all[t * 256 + 192 + d];
#pragma unroll
            for (int r = 0; r < 4; ++r) {
                const float ai = acc[0][r] + bi, af = acc[1][r] + bf,
                            ag = acc[2][r] + bg, ao = acc[3][r] + bov;
                const float c2 = fmaf(sigm(af), ccr[q][r], sigm(ai) * tanh_fast(ag));
                ccr[q][r] = c2;
                const float h2 = sigm(ao) * tanh_fast(c2);
                t_lds[wave][4 * g4 + r][16 * q + c] = f2b(h2);
                if (lastt) {
                    const int n = nb + 4 * g4 + r;
                    chf[n * 64 + d] = h2;
                    ccf[n * 64 + d] = c2;
                }
            }
        }
        ach0 = *(const bf16x8*)(&t_lds[wave][c][g4 * 8]);
        ach1 = *(const bf16x8*)(&t_lds[wave][c][32 + g4 * 8]);

        {
            f32x4 oa = (f32x4){0.f, 0.f, 0.f, 0.f};
            oa = __builtin_amdgcn_mfma_f32_16x16x32_bf16(ach0, woB0, oa, 0, 0, 0);
            oa = __builtin_amdgcn_mfma_f32_16x16x32_bf16(ach1, woB1, oa, 0, 0, 0);
            if (c < OUTx) {
                float* outp = out0 + (size_t)t * Nx * OUTx;
#pragma unroll
                for (int r = 0; r < 4; ++r)
                    outp[(nb + 4 * g4 + r) * OUTx + c] = oa[r] + bo_c;
            }
        }
    }
}

extern "C" void kernel_launch(void* const* d_in, const int* in_sizes, int n_in,
                              void* d_out, int out_size, void* d_ws, size_t ws_size,
                              hipStream_t stream) {
    const float* input   = (const float*)d_in[0];
    const float* cell_h0 = (const float*)d_in[1];
    const float* cell_c0 = (const float*)d_in[2];
    const float* graph_h0= (const float*)d_in[3];
    const float* graph_c0= (const float*)d_in[4];
    const float* W_dyn   = (const float*)d_in[5];
    const float* b_dyn   = (const float*)d_in[6];
    const float* W_gemb  = (const float*)d_in[7];
    const float* b_gemb  = (const float*)d_in[8];
    const float* Wih_g   = (const float*)d_in[9];
    const float* Whh_g   = (const float*)d_in[10];
    const float* bih_g   = (const float*)d_in[11];
    const float* bhh_g   = (const float*)d_in[12];
    const float* w_graph = (const float*)d_in[13];
    const float* Wih_c   = (const float*)d_in[14];
    const float* Whh_c   = (const float*)d_in[15];
    const float* bih_c   = (const float*)d_in[16];
    const float* bhh_c   = (const float*)d_in[17];
    const float* W_out   = (const float*)d_in[18];
    const float* b_out   = (const float*)d_in[19];

    float* out0 = (float*)d_out;
    float* chf = out0 + (size_t)Sx * Nx * OUTx;
    float* ccf = chf + (size_t)Nx * 64;
    float* ghf = ccf + (size_t)Nx * 64;
    float* gcf = ghf + (size_t)Nx * 64;

    const size_t ghb_bytes   = (size_t)Sx * Nx * 64 * 2;          // 256 MB
    const size_t small_bytes = (size_t)Sx * 256 * 4 + 256 * KG * 2 +
                               256 * KC * 2 + 16 * 64 * 2 +
                               64 * 256 * 4 + 256 * 4 + 256 * 4 +
                               (size_t)Sx * 16 * 64 * 4 + 2048;
    const size_t pb_small = (size_t)Sx * GRIDA * 64 * 4;          // 2 MB
    const size_t pb_big   = (size_t)Sx * NWAVE * 64 * 4;          // 33.5 MB

    char* base = (char*)d_ws;
    const bool use_pt = (ws_size >= ghb_bytes + small_bytes + pb_small);
    const bool use_pw = use_pt && (ws_size >= ghb_bytes + small_bytes + pb_big);

    size_t off = 0;
    ushort* ghb = nullptr;
    if (use_pt) { ghb = (ushort*)base; off += ghb_bytes; }
    float*  bias_all= (float*)(base + off); off += (size_t)Sx * 256 * 4;
    ushort* Wg      = (ushort*)(base + off); off += 256 * KG * 2;
    ushort* Wc      = (ushort*)(base + off); off += 256 * KC * 2;
    ushort* WoB     = (ushort*)(base + off); off += 16 * 64 * 2;
    float*  Wfold2  = (float*)(base + off); off += 64 * 256 * 4;
    float*  bsum_g  = (float*)(base + off); off += 256 * 4;
    float*  bC0     = (float*)(base + off); off += 256 * 4;
    float*  p2      = (float*)(base + off); off += (size_t)Sx * 16 * 64 * 4;
    off = (off + 255) & ~(size_t)255;
    float*  partials= (float*)(base + off);

    k_prep<<<64, 256, 0, stream>>>(Wih_g, Whh_g, bih_g, bhh_g, w_graph,
                                   Wih_c, Whh_c, bih_c, bhh_c, W_out,
                                   Wg, Wc, WoB, Wfold2, bsum_g, bC0);

    if (use_pw) {
        k_graph_all<1><<<GRIDA, TPB, 0, stream>>>(input, graph_h0, graph_c0,
                                                  W_gemb, b_gemb, Wg, bsum_g,
                                                  partials, ghb, ghf, gcf);
        k_red1<<<Sx * 16, 256, 0, stream>>>(partials, p2);
        k_bias<<<Sx, 256, 0, stream>>>(p2, 16, Wfold2, bC0, bias_all);
    } else {
        k_graph_all<0><<<GRIDA, TPB, 0, stream>>>(input, graph_h0, graph_c0,
                                                  W_gemb, b_gemb, Wg, bsum_g,
                                                  partials, ghb, ghf, gcf);
        k_bias<<<Sx, 256, 0, stream>>>(partials, GRIDA, Wfold2, bC0, bias_all);
    }

    if (use_pt) {
        k_cell_pt<<<GRIDA, TPB, 0, stream>>>(input, ghb, cell_h0, cell_c0,
                                             W_dyn, b_dyn, Wc, bias_all,
                                             WoB, b_out, out0, chf, ccf);
    } else {
        k_cell_rc<<<GRIDF, TPBF, 0, stream>>>(input, graph_h0, graph_c0,
                                              cell_h0, cell_c0,
                                              W_gemb, b_gemb, Wg, bsum_g,
                                              W_dyn, b_dyn, Wc, bias_all,
                                              WoB, b_out, out0, chf, ccf);
    }
}

// Round 19
// 494.915 us; speedup vs baseline: 1.1053x; 1.1053x over previous
//
#include <hip/hip_runtime.h>
#include <hip/hip_bf16.h>

// GraphLSTM v15 = round-18 + log2e folded into gate weights (exp2 direct).
// Round-18: C is issue-bound (VALU 66% + MFMA 25%); each __expf costs an
// extra v_mul by log2e. Fold log2e (i,f,o rows) / 2*log2e (g rows) into
// Wg/Wc/bsum_g/bC0/Wfold2 in k_prep (f32, before bf16 rounding) ->
// sigm = rcp(1+exp2(-y)), g-tanh = fma(-2,rcp(1+exp2(y)),1): zero muls.
// c2-tanh keeps one const mul. ~96 VALU issues/thread/step removed in A+C.
// Also: bias_all staged in C's LDS (149KB total, still 1 block/CU).

#define Sx    32
#define Nx    65536
#define OUTx  5
#define KG    96
#define KC    160
#define GRIDA 256             // A/C blocks (16 waves)
#define TPB   1024
#define NWAVE (GRIDA * 16)    // 4096 per-wave partial slots
#define GRIDF 512             // rc fallback geometry
#define TPBF  512

typedef __attribute__((ext_vector_type(4))) float f32x4;
typedef __attribute__((ext_vector_type(8))) short bf16x8;
typedef unsigned short ushort;
typedef unsigned int uint;

#define TL2 2.8853900817779268f   // 2*log2(e)

// pre-scaled activations: y already multiplied by log2e (i,f,o) / 2log2e (g)
__device__ __forceinline__ float sigm2(float y) {
    return __builtin_amdgcn_rcpf(1.f + __builtin_amdgcn_exp2f(-y));
}
__device__ __forceinline__ float tgate(float y) {   // tanh, y = 2x*log2e
    return fmaf(-2.f, __builtin_amdgcn_rcpf(1.f + __builtin_amdgcn_exp2f(y)), 1.f);
}
__device__ __forceinline__ float tanh2(float x) {   // tanh of unscaled x
    return fmaf(-2.f, __builtin_amdgcn_rcpf(1.f + __builtin_amdgcn_exp2f(x * TL2)), 1.f);
}
__device__ __forceinline__ ushort f2b(float x) {
    uint u = __float_as_uint(x);
    u += 0x7fffu + ((u >> 16) & 1u);   // RNE
    return (ushort)(u >> 16);
}
__device__ __forceinline__ ushort f2b_n(float x) {
    __hip_bfloat16 b = __float2bfloat16(x);
    return *reinterpret_cast<ushort*>(&b);
}
__device__ __forceinline__ int swz(int row, int col) {
    return col ^ (((row >> 2) & 3) << 4);
}

// ---------------- weight prep (fragment-major packing + log2e fold) -------
__global__ __launch_bounds__(256) void k_prep(
    const float* __restrict__ Wih_g, const float* __restrict__ Whh_g,
    const float* __restrict__ bih_g, const float* __restrict__ bhh_g,
    const float* __restrict__ wgr,
    const float* __restrict__ Wih_c, const float* __restrict__ Whh_c,
    const float* __restrict__ bih_c, const float* __restrict__ bhh_c,
    const float* __restrict__ Wout,
    ushort* __restrict__ Wg, ushort* __restrict__ Wc,
    ushort* __restrict__ WoB,
    float* __restrict__ Wfold2,
    float* __restrict__ bsum_g, float* __restrict__ bC0)
{
    const int tid = blockIdx.x * 256 + threadIdx.x;
    const int nt = gridDim.x * 256;
    const float L2E = 1.4426950408889634f;
    // gate scale: i,f,o -> log2e ; g -> 2*log2e   (gate index = g in packing)
    // Wg packed: [(q*4+g)*3 + ks][lane(=g4*16+c)][j:8]
    for (int o = tid; o < 256 * KG; o += nt) {
        const int j = o & 7, lane = (o >> 3) & 63;
        const int ks = (o >> 9) % 3, gq = (o >> 9) / 3;
        const int q = gq >> 2, g = gq & 3;
        const int col = 16 * (4 * g + q) + (lane & 15);
        const int k = ks * 32 + (lane >> 4) * 8 + j;
        float v = (k < 32) ? Wih_g[col * 32 + k] : Whh_g[col * 64 + (k - 32)];
        v *= (g == 2) ? (2.f * L2E) : L2E;
        Wg[o] = f2b(v);
    }
    // Wc packed: [(q*4+g)*5 + ks][lane][j:8]
    for (int o = tid; o < 256 * KC; o += nt) {
        const int j = o & 7, lane = (o >> 3) & 63;
        const int ks = (o >> 9) % 5, gq = (o >> 9) / 5;
        const int q = gq >> 2, g = gq & 3;
        const int col = 16 * (4 * g + q) + (lane & 15);
        const int k = ks * 32 + (lane >> 4) * 8 + j;
        float v;
        if (k < 32) v = Wih_c[col * 64 + k];
        else if (k < 96) {
            int d = k - 32; float a = 0.f;
            for (int jj = 0; jj < 32; ++jj)
                a = fmaf(wgr[d * 32 + jj], Wih_c[col * 64 + 32 + jj], a);
            v = -a;
        } else v = Whh_c[col * 64 + (k - 96)];
        v *= (g == 2) ? (2.f * L2E) : L2E;
        Wc[o] = f2b(v);
    }
    for (int idx = tid; idx < 16 * 64; idx += nt) {
        int col = idx >> 6, k = idx & 63;
        WoB[idx] = (col < OUTx) ? f2b(Wout[col * 64 + k]) : (ushort)0;
    }
    for (int idx = tid; idx < 64 * 256; idx += nt) {
        int k = idx >> 8, col = idx & 255;
        float a = 0.f;
        for (int j = 0; j < 32; ++j)
            a = fmaf(wgr[k * 32 + j], Wih_c[col * 64 + 32 + j], a);
        a *= ((col >> 6) == 2) ? (2.f * L2E) : L2E;
        Wfold2[idx] = a;
    }
    if (tid < 256) {
        const float s = ((tid >> 6) == 2) ? (2.f * L2E) : L2E;
        bsum_g[tid] = (bih_g[tid] + bhh_g[tid]) * s;
        bC0[tid]    = (bih_c[tid] + bhh_c[tid]) * s;
    }
}

// ---------------- A: graph LSTM, all steps -------------------------------
template <int PW>
__global__ __launch_bounds__(TPB, 2) void k_graph_all(
    const float* __restrict__ input,
    const float* __restrict__ gh0, const float* __restrict__ gc0,
    const float* __restrict__ Wge, const float* __restrict__ bge,
    const ushort* __restrict__ Wg, const float* __restrict__ bsum_g,
    float* __restrict__ partials,
    ushort* __restrict__ ghb,
    float* __restrict__ ghf, float* __restrict__ gcf)
{
    const int tid = threadIdx.x;
    const int wave = tid >> 6, lane = tid & 63;
    const int c = lane & 15, g4 = lane >> 4;
    const int nb = blockIdx.x * 256 + wave * 16;
    const int na = nb + c;

    __shared__ __align__(16) ushort lWg[256 * KG];
    __shared__ __align__(16) ushort t_lds[16][16][72];
    __shared__ float wsum[PW ? 1 : 2][16][64];

    {
        const uint* src = (const uint*)Wg;
        uint* dst = (uint*)lWg;
        for (int i = tid; i < 256 * (KG / 2); i += TPB) dst[i] = src[i];
    }
    __syncthreads();

    float bsg[4][4];
#pragma unroll
    for (int q = 0; q < 4; ++q)
#pragma unroll
        for (int g = 0; g < 4; ++g)
            bsg[q][g] = bsum_g[64 * g + 16 * q + c];

    float gcr[4][4];
#pragma unroll
    for (int q = 0; q < 4; ++q)
#pragma unroll
        for (int r = 0; r < 4; ++r)
            gcr[q][r] = gc0[(nb + 4 * g4 + r) * 64 + 16 * q + c];
    bf16x8 agh0, agh1;
#pragma unroll
    for (int j = 0; j < 8; ++j) {
        agh0[j] = (short)f2b(gh0[na * 64 + g4 * 8 + j]);
        agh1[j] = (short)f2b(gh0[na * 64 + 32 + g4 * 8 + j]);
    }
    const int lane8 = lane * 8;

#pragma unroll 1
    for (int t = 0; t < Sx; ++t) {
        const float* frame = input + (size_t)t * Nx * 2;
        const float f0 = frame[2 * na], f1 = frame[2 * na + 1];
        const int lastt = (t == Sx - 1);
        bf16x8 a0;
#pragma unroll
        for (int j = 0; j < 8; ++j) {
            const int k = g4 * 8 + j;
            float v = fmaf(f1, Wge[2 * k + 1], fmaf(f0, Wge[2 * k], bge[k]));
            a0[j] = (short)f2b_n(fmaxf(v, 0.f));
        }
        float hsq[4];
#pragma unroll 2
        for (int q = 0; q < 4; ++q) {
            f32x4 acc[4];
#pragma unroll
            for (int g = 0; g < 4; ++g) {
                acc[g] = (f32x4){0.f, 0.f, 0.f, 0.f};
                const ushort* wp = lWg + ((q * 4 + g) * 3) * 512 + lane8;
                bf16x8 b0 = *(const bf16x8*)(wp);
                bf16x8 b1 = *(const bf16x8*)(wp + 512);
                bf16x8 b2 = *(const bf16x8*)(wp + 1024);
                acc[g] = __builtin_amdgcn_mfma_f32_16x16x32_bf16(a0,   b0, acc[g], 0, 0, 0);
                acc[g] = __builtin_amdgcn_mfma_f32_16x16x32_bf16(agh0, b1, acc[g], 0, 0, 0);
                acc[g] = __builtin_amdgcn_mfma_f32_16x16x32_bf16(agh1, b2, acc[g], 0, 0, 0);
            }
            const int d = 16 * q + c;
            float s_r = 0.f;
#pragma unroll
            for (int r = 0; r < 4; ++r) {
                const float ai = acc[0][r] + bsg[q][0], af = acc[1][r] + bsg[q][1],
                            ag = acc[2][r] + bsg[q][2], ao = acc[3][r] + bsg[q][3];
                const float c2 = fmaf(sigm2(af), gcr[q][r], sigm2(ai) * tgate(ag));
                gcr[q][r] = c2;
                const float h2 = sigm2(ao) * tanh2(c2);
                const int row = 4 * g4 + r;
                t_lds[wave][row][swz(row, 16 * q + c)] = f2b_n(h2);
                if (lastt) {
                    const int n = nb + row;
                    ghf[n * 64 + d] = h2;
                    gcf[n * 64 + d] = c2;
                }
                s_r += h2;
            }
            hsq[q] = s_r;
        }
#pragma unroll
        for (int q = 0; q < 4; ++q) {
            float v = hsq[q];
            v += __shfl_xor(v, 16);
            v += __shfl_xor(v, 32);
            hsq[q] = v;
        }
        if (PW) {
            float v = (g4 == 0) ? hsq[0] : (g4 == 1) ? hsq[1]
                    : (g4 == 2) ? hsq[2] : hsq[3];
            const int gw = blockIdx.x * 16 + wave;
            partials[((size_t)t * NWAVE + gw) * 64 + 16 * g4 + c] = v;
        } else {
            if (g4 == 0) {
#pragma unroll
                for (int q = 0; q < 4; ++q) wsum[t & 1][wave][16 * q + c] = hsq[q];
            }
            __syncthreads();
        }
        agh0 = *(const bf16x8*)(&t_lds[wave][c][swz(c, g4 * 8)]);
        agh1 = *(const bf16x8*)(&t_lds[wave][c][swz(c, 32 + g4 * 8)]);
        if (ghb) {
            ushort* gp = ghb + ((size_t)t * Nx + na) * 64 + g4 * 8;
            *(bf16x8*)(gp)      = agh0;
            *(bf16x8*)(gp + 32) = agh1;
        }
        if (!PW) {
            if (tid < 64) {
                float a = 0.f;
#pragma unroll
                for (int w8 = 0; w8 < 16; ++w8) a += wsum[t & 1][w8][tid];
                partials[((size_t)t * GRIDA + blockIdx.x) * 64 + tid] = a;
            }
        }
    }
}

// ---------------- B1: first-stage reduce (512 blocks) ----------------------
__global__ __launch_bounds__(256) void k_red1(
    const float* __restrict__ partials,   // [S][NWAVE][64]
    float* __restrict__ p2)               // [S][16][64]
{
    const int t = blockIdx.x >> 4, s = blockIdx.x & 15;
    const int tid = threadIdx.x;
    const int d = tid & 63, j = tid >> 6;
    __shared__ float red[4][64];
    const float* bp = partials + ((size_t)t * NWAVE + s * 256) * 64;
    float a = 0.f;
    for (int b = j; b < 256; b += 4)
        a += bp[b * 64 + d];
    red[j][d] = a;
    __syncthreads();
    if (tid < 64)
        p2[((size_t)t * 16 + s) * 64 + tid] =
            red[0][tid] + red[1][tid] + red[2][tid] + red[3][tid];
}

// ---------------- B2: per-step bias ----------------------------------------
__global__ __launch_bounds__(256) void k_bias(
    const float* __restrict__ partials,   // [S][nw][64]
    int nw,
    const float* __restrict__ Wfold2, const float* __restrict__ bC0,
    float* __restrict__ bias_all)         // [S][256]
{
    const int t = blockIdx.x, tid = threadIdx.x;
    __shared__ float red[4][64];
    __shared__ float S[64];
    const int d = tid & 63, j = tid >> 6;
    float a = 0.f;
    for (int b = j; b < nw; b += 4)
        a += partials[((size_t)t * nw + b) * 64 + d];
    red[j][d] = a;
    __syncthreads();
    if (tid < 64) S[tid] = red[0][tid] + red[1][tid] + red[2][tid] + red[3][tid];
    __syncthreads();
    float bv = bC0[tid];
#pragma unroll
    for (int k = 0; k < 64; ++k) bv = fmaf(S[k], Wfold2[k * 256 + tid], bv);
    bias_all[t * 256 + tid] = bv;
}

// ---------------- C (pass-through): cell LSTM only ------------------------
__global__ __launch_bounds__(TPB, 2) void k_cell_pt(
    const float* __restrict__ input,
    const ushort* __restrict__ ghb,
    const float* __restrict__ ch0, const float* __restrict__ cc0,
    const float* __restrict__ Wdy, const float* __restrict__ bdy,
    const ushort* __restrict__ Wc, const float* __restrict__ bias_all,
    const ushort* __restrict__ WoB, const float* __restrict__ bo5,
    float* __restrict__ out0,
    float* __restrict__ chf, float* __restrict__ ccf)
{
    const int tid = threadIdx.x;
    const int wave = tid >> 6, lane = tid & 63;
    const int c = lane & 15, g4 = lane >> 4;
    const int nb = blockIdx.x * 256 + wave * 16;
    const int na = nb + c;

    __shared__ __align__(16) ushort lWc[256 * KC];       // 80 KB packed
    __shared__ __align__(16) ushort t_lds[16][16][72];   // 36.9 KB
    __shared__ float lBias[Sx * 256];                    // 32 KB

    {
        const uint* src2 = (const uint*)Wc;
        uint* dst2 = (uint*)lWc;
        for (int i = tid; i < 256 * (KC / 2); i += TPB) dst2[i] = src2[i];
        for (int i = tid; i < Sx * 256; i += TPB) lBias[i] = bias_all[i];
    }
    __syncthreads();

    float ccr[4][4];
#pragma unroll
    for (int q = 0; q < 4; ++q)
#pragma unroll
        for (int r = 0; r < 4; ++r)
            ccr[q][r] = cc0[(nb + 4 * g4 + r) * 64 + 16 * q + c];
    bf16x8 ach0, ach1;
#pragma unroll
    for (int j = 0; j < 8; ++j) {
        ach0[j] = (short)f2b(ch0[na * 64 + g4 * 8 + j]);
        ach1[j] = (short)f2b(ch0[na * 64 + 32 + g4 * 8 + j]);
    }
    bf16x8 woB0 = *(const bf16x8*)(WoB + c * 64 + g4 * 8);
    bf16x8 woB1 = *(const bf16x8*)(WoB + c * 64 + 32 + g4 * 8);
    const float bo_c = (c < OUTx) ? bo5[c] : 0.f;
    const int lane8 = lane * 8;

#pragma unroll 1
    for (int t = 0; t < Sx; ++t) {
        const float* frame = input + (size_t)t * Nx * 2;
        const float f0 = frame[2 * na], f1 = frame[2 * na + 1];
        const int lastt = (t == Sx - 1);

        const ushort* gp = ghb + ((size_t)t * Nx + na) * 64 + g4 * 8;
        bf16x8 agh0 = *(const bf16x8*)(gp);
        bf16x8 agh1 = *(const bf16x8*)(gp + 32);

        bf16x8 a0c;
#pragma unroll
        for (int j = 0; j < 8; ++j) {
            const int k = g4 * 8 + j;
            float v = fmaf(f1, Wdy[2 * k + 1], fmaf(f0, Wdy[2 * k], bdy[k]));
            a0c[j] = (short)f2b_n(fmaxf(v, 0.f));
        }
#pragma unroll 1
        for (int q = 0; q < 4; ++q) {
            f32x4 acc[4];
#pragma unroll
            for (int g = 0; g < 4; ++g) {
                acc[g] = (f32x4){0.f, 0.f, 0.f, 0.f};
                const ushort* wp = lWc + ((q * 4 + g) * 5) * 512 + lane8;
                bf16x8 b0 = *(const bf16x8*)(wp);
                bf16x8 b1 = *(const bf16x8*)(wp + 512);
                bf16x8 b2 = *(const bf16x8*)(wp + 1024);
                bf16x8 b3 = *(const bf16x8*)(wp + 1536);
                bf16x8 b4 = *(const bf16x8*)(wp + 2048);
                acc[g] = __builtin_amdgcn_mfma_f32_16x16x32_bf16(a0c,  b0, acc[g], 0, 0, 0);
                acc[g] = __builtin_amdgcn_mfma_f32_16x16x32_bf16(agh0, b1, acc[g], 0, 0, 0);
                acc[g] = __builtin_amdgcn_mfma_f32_16x16x32_bf16(agh1, b2, acc[g], 0, 0, 0);
                acc[g] = __builtin_amdgcn_mfma_f32_16x16x32_bf16(ach0, b3, acc[g], 0, 0, 0);
                acc[g] = __builtin_amdgcn_mfma_f32_16x16x32_bf16(ach1, b4, acc[g], 0, 0, 0);
            }
            const int d = 16 * q + c;
            const float bi = lBias[t * 256 + d],
                        bf = lBias[t * 256 + 64 + d],
                        bg = lBias[t * 256 + 128 + d],
                        bov = lBias[t * 256 + 192 + d];
#pragma unroll
            for (int r = 0; r < 4; ++r) {
                const float ai = acc[0][r] + bi, af = acc[1][r] + bf,
                            ag = acc[2][r] + bg, ao = acc[3][r] + bov;
                const float c2 = fmaf(sigm2(af), ccr[q][r], sigm2(ai) * tgate(ag));
                ccr[q][r] = c2;
                const float h2 = sigm2(ao) * tanh2(c2);
                const int row = 4 * g4 + r;
                t_lds[wave][row][swz(row, 16 * q + c)] = f2b_n(h2);
                if (lastt) {
                    const int n = nb + row;
                    chf[n * 64 + d] = h2;
                    ccf[n * 64 + d] = c2;
                }
            }
        }
        ach0 = *(const bf16x8*)(&t_lds[wave][c][swz(c, g4 * 8)]);
        ach1 = *(const bf16x8*)(&t_lds[wave][c][swz(c, 32 + g4 * 8)]);

        {
            f32x4 oa = (f32x4){0.f, 0.f, 0.f, 0.f};
            oa = __builtin_amdgcn_mfma_f32_16x16x32_bf16(ach0, woB0, oa, 0, 0, 0);
            oa = __builtin_amdgcn_mfma_f32_16x16x32_bf16(ach1, woB1, oa, 0, 0, 0);
            if (c < OUTx) {
                float* outp = out0 + (size_t)t * Nx * OUTx;
#pragma unroll
                for (int r = 0; r < 4; ++r)
                    outp[(nb + 4 * g4 + r) * OUTx + c] = oa[r] + bo_c;
            }
        }
    }
}

// ---------------- C (fallback): graph recompute + cell --------------------
__global__ __launch_bounds__(TPBF, 2) void k_cell_rc(
    const float* __restrict__ input,
    const float* __restrict__ gh0, const float* __restrict__ gc0,
    const float* __restrict__ ch0, const float* __restrict__ cc0,
    const float* __restrict__ Wge, const float* __restrict__ bge,
    const ushort* __restrict__ Wg, const float* __restrict__ bsum_g,
    const float* __restrict__ Wdy, const float* __restrict__ bdy,
    const ushort* __restrict__ Wc, const float* __restrict__ bias_all,
    const ushort* __restrict__ WoB, const float* __restrict__ bo5,
    float* __restrict__ out0,
    float* __restrict__ chf, float* __restrict__ ccf)
{
    const int tid = threadIdx.x;
    const int wave = tid >> 6, lane = tid & 63;
    const int c = lane & 15, g4 = lane >> 4;
    const int nb = blockIdx.x * 128 + wave * 16;
    const int na = nb + c;

    __shared__ __align__(16) ushort lWg[256 * KG];
    __shared__ __align__(16) ushort lWc[256 * KC];
    __shared__ __align__(16) ushort t_lds[8][16][72];

    {
        const uint* src = (const uint*)Wg;
        uint* dst = (uint*)lWg;
        for (int i = tid; i < 256 * (KG / 2); i += TPBF) dst[i] = src[i];
        const uint* src2 = (const uint*)Wc;
        uint* dst2 = (uint*)lWc;
        for (int i = tid; i < 256 * (KC / 2); i += TPBF) dst2[i] = src2[i];
    }
    __syncthreads();

    float gcr[4][4], ccr[4][4];
#pragma unroll
    for (int q = 0; q < 4; ++q)
#pragma unroll
        for (int r = 0; r < 4; ++r) {
            const int n = nb + 4 * g4 + r, d = 16 * q + c;
            gcr[q][r] = gc0[n * 64 + d];
            ccr[q][r] = cc0[n * 64 + d];
        }
    bf16x8 agh0, agh1, ach0, ach1;
#pragma unroll
    for (int j = 0; j < 8; ++j) {
        agh0[j] = (short)f2b(gh0[na * 64 + g4 * 8 + j]);
        agh1[j] = (short)f2b(gh0[na * 64 + 32 + g4 * 8 + j]);
        ach0[j] = (short)f2b(ch0[na * 64 + g4 * 8 + j]);
        ach1[j] = (short)f2b(ch0[na * 64 + 32 + g4 * 8 + j]);
    }
    bf16x8 woB0 = *(const bf16x8*)(WoB + c * 64 + g4 * 8);
    bf16x8 woB1 = *(const bf16x8*)(WoB + c * 64 + 32 + g4 * 8);
    const float bo_c = (c < OUTx) ? bo5[c] : 0.f;
    const int lane8 = lane * 8;

#pragma unroll 1
    for (int t = 0; t < Sx; ++t) {
        const float* frame = input + (size_t)t * Nx * 2;
        const float f0 = frame[2 * na], f1 = frame[2 * na + 1];
        const int lastt = (t == Sx - 1);

        bf16x8 a0;
#pragma unroll
        for (int j = 0; j < 8; ++j) {
            const int k = g4 * 8 + j;
            float v = fmaf(f1, Wge[2 * k + 1], fmaf(f0, Wge[2 * k], bge[k]));
            a0[j] = (short)f2b(fmaxf(v, 0.f));
        }
#pragma unroll 1
        for (int q = 0; q < 4; ++q) {
            f32x4 acc[4];
#pragma unroll
            for (int g = 0; g < 4; ++g) {
                acc[g] = (f32x4){0.f, 0.f, 0.f, 0.f};
                const ushort* wp = lWg + ((q * 4 + g) * 3) * 512 + lane8;
                bf16x8 b0 = *(const bf16x8*)(wp);
                bf16x8 b1 = *(const bf16x8*)(wp + 512);
                bf16x8 b2 = *(const bf16x8*)(wp + 1024);
                acc[g] = __builtin_amdgcn_mfma_f32_16x16x32_bf16(a0,   b0, acc[g], 0, 0, 0);
                acc[g] = __builtin_amdgcn_mfma_f32_16x16x32_bf16(agh0, b1, acc[g], 0, 0, 0);
                acc[g] = __builtin_amdgcn_mfma_f32_16x16x32_bf16(agh1, b2, acc[g], 0, 0, 0);
            }
            const int d = 16 * q + c;
            const float bi = bsum_g[d], bf = bsum_g[64 + d],
                        bg = bsum_g[128 + d], bo = bsum_g[192 + d];
#pragma unroll
            for (int r = 0; r < 4; ++r) {
                const float ai = acc[0][r] + bi, af = acc[1][r] + bf,
                            ag = acc[2][r] + bg, ao = acc[3][r] + bo;
                const float c2 = fmaf(sigm2(af), gcr[q][r], sigm2(ai) * tgate(ag));
                gcr[q][r] = c2;
                const float h2 = sigm2(ao) * tanh2(c2);
                t_lds[wave][4 * g4 + r][16 * q + c] = f2b(h2);
            }
        }
        agh0 = *(const bf16x8*)(&t_lds[wave][c][g4 * 8]);
        agh1 = *(const bf16x8*)(&t_lds[wave][c][32 + g4 * 8]);

        bf16x8 a0c;
#pragma unroll
        for (int j = 0; j < 8; ++j) {
            const int k = g4 * 8 + j;
            float v = fmaf(f1, Wdy[2 * k + 1], fmaf(f0, Wdy[2 * k], bdy[k]));
            a0c[j] = (short)f2b(fmaxf(v, 0.f));
        }
#pragma unroll 1
        for (int q = 0; q < 4; ++q) {
            f32x4 acc[4];
#pragma unroll
            for (int g = 0; g < 4; ++g) {
                acc[g] = (f32x4){0.f, 0.f, 0.f, 0.f};
                const ushort* wp = lWc + ((q * 4 + g) * 5) * 512 + lane8;
                bf16x8 b0 = *(const bf16x8*)(wp);
                bf16x8 b1 = *(const bf16x8*)(wp + 512);
                bf16x8 b2 = *(const bf16x8*)(wp + 1024);
                bf16x8 b3 = *(const bf16x8*)(wp + 1536);
                bf16x8 b4 = *(const bf16x8*)(wp + 2048);
                acc[g] = __builtin_amdgcn_mfma_f32_16x16x32_bf16(a0c,  b0, acc[g], 0, 0, 0);
                acc[g] = __builtin_amdgcn_mfma_f32_16x16x32_bf16(agh0, b1, acc[g], 0, 0, 0);
                acc[g] = __builtin_amdgcn_mfma_f32_16x16x32_bf16(agh1, b2, acc[g], 0, 0, 0);
                acc[g] = __builtin_amdgcn_mfma_f32_16x16x32_bf16(ach0, b3, acc[g], 0, 0, 0);
                acc[g] = __builtin_amdgcn_mfma_f32_16x16x32_bf16(ach1, b4, acc[g], 0, 0, 0);
            }
            const int d = 16 * q + c;
            const float bi = bias_all[t * 256 + d],
                        bf = bias_all[t * 256 + 64 + d],
                        bg = bias_all[t * 256 + 128 + d],
                        bov = bias_all[t * 256 + 192 + d];
#pragma unroll
            for (int r = 0; r < 4; ++r) {
                const float ai = acc[0][r] + bi, af = acc[1][r] + bf,
                            ag = acc[2][r] + bg, ao = acc[3][r] + bov;
                const float c2 = fmaf(sigm2(af), ccr[q][r], sigm2(ai) * tgate(ag));
                ccr[q][r] = c2;
                const float h2 = sigm2(ao) * tanh2(c2);
                t_lds[wave][4 * g4 + r][16 * q + c] = f2b(h2);
                if (lastt) {
                    const int n = nb + 4 * g4 + r;
                    chf[n * 64 + d] = h2;
                    ccf[n * 64 + d] = c2;
                }
            }
        }
        ach0 = *(const bf16x8*)(&t_lds[wave][c][g4 * 8]);
        ach1 = *(const bf16x8*)(&t_lds[wave][c][32 + g4 * 8]);

        {
            f32x4 oa = (f32x4){0.f, 0.f, 0.f, 0.f};
            oa = __builtin_amdgcn_mfma_f32_16x16x32_bf16(ach0, woB0, oa, 0, 0, 0);
            oa = __builtin_amdgcn_mfma_f32_16x16x32_bf16(ach1, woB1, oa, 0, 0, 0);
            if (c < OUTx) {
                float* outp = out0 + (size_t)t * Nx * OUTx;
#pragma unroll
                for (int r = 0; r < 4; ++r)
                    outp[(nb + 4 * g4 + r) * OUTx + c] = oa[r] + bo_c;
            }
        }
    }
}

extern "C" void kernel_launch(void* const* d_in, const int* in_sizes, int n_in,
                              void* d_out, int out_size, void* d_ws, size_t ws_size,
                              hipStream_t stream) {
    const float* input   = (const float*)d_in[0];
    const float* cell_h0 = (const float*)d_in[1];
    const float* cell_c0 = (const float*)d_in[2];
    const float* graph_h0= (const float*)d_in[3];
    const float* graph_c0= (const float*)d_in[4];
    const float* W_dyn   = (const float*)d_in[5];
    const float* b_dyn   = (const float*)d_in[6];
    const float* W_gemb  = (const float*)d_in[7];
    const float* b_gemb  = (const float*)d_in[8];
    const float* Wih_g   = (const float*)d_in[9];
    const float* Whh_g   = (const float*)d_in[10];
    const float* bih_g   = (const float*)d_in[11];
    const float* bhh_g   = (const float*)d_in[12];
    const float* w_graph = (const float*)d_in[13];
    const float* Wih_c   = (const float*)d_in[14];
    const float* Whh_c   = (const float*)d_in[15];
    const float* bih_c   = (const float*)d_in[16];
    const float* bhh_c   = (const float*)d_in[17];
    const float* W_out   = (const float*)d_in[18];
    const float* b_out   = (const float*)d_in[19];

    float* out0 = (float*)d_out;
    float* chf = out0 + (size_t)Sx * Nx * OUTx;
    float* ccf = chf + (size_t)Nx * 64;
    float* ghf = ccf + (size_t)Nx * 64;
    float* gcf = ghf + (size_t)Nx * 64;

    const size_t ghb_bytes   = (size_t)Sx * Nx * 64 * 2;          // 256 MB
    const size_t small_bytes = (size_t)Sx * 256 * 4 + 256 * KG * 2 +
                               256 * KC * 2 + 16 * 64 * 2 +
                               64 * 256 * 4 + 256 * 4 + 256 * 4 +
                               (size_t)Sx * 16 * 64 * 4 + 2048;
    const size_t pb_small = (size_t)Sx * GRIDA * 64 * 4;          // 2 MB
    const size_t pb_big   = (size_t)Sx * NWAVE * 64 * 4;          // 33.5 MB

    char* base = (char*)d_ws;
    const bool use_pt = (ws_size >= ghb_bytes + small_bytes + pb_small);
    const bool use_pw = use_pt && (ws_size >= ghb_bytes + small_bytes + pb_big);

    size_t off = 0;
    ushort* ghb = nullptr;
    if (use_pt) { ghb = (ushort*)base; off += ghb_bytes; }
    float*  bias_all= (float*)(base + off); off += (size_t)Sx * 256 * 4;
    ushort* Wg      = (ushort*)(base + off); off += 256 * KG * 2;
    ushort* Wc      = (ushort*)(base + off); off += 256 * KC * 2;
    ushort* WoB     = (ushort*)(base + off); off += 16 * 64 * 2;
    float*  Wfold2  = (float*)(base + off); off += 64 * 256 * 4;
    float*  bsum_g  = (float*)(base + off); off += 256 * 4;
    float*  bC0     = (float*)(base + off); off += 256 * 4;
    float*  p2      = (float*)(base + off); off += (size_t)Sx * 16 * 64 * 4;
    off = (off + 255) & ~(size_t)255;
    float*  partials= (float*)(base + off);

    k_prep<<<64, 256, 0, stream>>>(Wih_g, Whh_g, bih_g, bhh_g, w_graph,
                                   Wih_c, Whh_c, bih_c, bhh_c, W_out,
                                   Wg, Wc, WoB, Wfold2, bsum_g, bC0);

    if (use_pw) {
        k_graph_all<1><<<GRIDA, TPB, 0, stream>>>(input, graph_h0, graph_c0,
                                                  W_gemb, b_gemb, Wg, bsum_g,
                                                  partials, ghb, ghf, gcf);
        k_red1<<<Sx * 16, 256, 0, stream>>>(partials, p2);
        k_bias<<<Sx, 256, 0, stream>>>(p2, 16, Wfold2, bC0, bias_all);
    } else {
        k_graph_all<0><<<GRIDA, TPB, 0, stream>>>(input, graph_h0, graph_c0,
                                                  W_gemb, b_gemb, Wg, bsum_g,
                                                  partials, ghb, ghf, gcf);
        k_bias<<<Sx, 256, 0, stream>>>(partials, GRIDA, Wfold2, bC0, bias_all);
    }

    if (use_pt) {
        k_cell_pt<<<GRIDA, TPB, 0, stream>>>(input, ghb, cell_h0, cell_c0,
                                             W_dyn, b_dyn, Wc, bias_all,
                                             WoB, b_out, out0, chf, ccf);
    } else {
        k_cell_rc<<<GRIDF, TPBF, 0, stream>>>(input, graph_h0, graph_c0,
                                              cell_h0, cell_c0,
                                              W_gemb, b_gemb, Wg, bsum_g,
                                              W_dyn, b_dyn, Wc, bias_all,
                                              WoB, b_out, out0, chf, ccf);
    }
}